// Round 1
// 7215.877 us; speedup vs baseline: 1.6272x; 1.6272x over previous
//
#include <hip/hip_runtime.h>
#include <hip/hip_fp16.h>

#define LOG2E 1.44269504088896340736f
#define BB 256
#define TT 128
#define SS 128
#define UU 256
// |dv| threshold for "unfold was identity". Skip error is O(thr) << f16 noise (2e-3).
#define CONV_EPS 4e-5f

// ---------------- parameter precompute ----------------
// sigmoid(sigma*(v-mu)) = 1/(1+2^(a*v+b)), a=-sigma*log2e, b=sigma*mu*log2e
// wsel = (softplus(w),0) if erev>0 else (0,softplus(w))  ->  num=P-N, den=P+N
// packed per pair: uint2{ half2(a,b), half2(wP,wN) }  (8 bytes)
__global__ __launch_bounds__(256) void prep_kernel(
    const float* __restrict__ sensory_w, const float* __restrict__ sensory_mu,
    const float* __restrict__ sensory_sigma, const float* __restrict__ sensory_erev,
    const float* __restrict__ w, const float* __restrict__ mu,
    const float* __restrict__ sigma, const float* __restrict__ erev,
    const float* __restrict__ gleak, const float* __restrict__ vleak,
    const float* __restrict__ cm,
    uint2* __restrict__ rabw, uint2* __restrict__ sabw,
    float* __restrict__ cmt, float* __restrict__ gnum, float* __restrict__ cden)
{
    int e = blockIdx.x * 256 + threadIdx.x;
    if (e < UU * UU) {
        float sg = sigma[e], m = mu[e];
        float wp = log1pf(expf(w[e]));
        bool pos = erev[e] > 0.0f;
        __half2 ab = __floats2half2_rn(-sg * LOG2E, sg * m * LOG2E);
        __half2 ws = __floats2half2_rn(pos ? wp : 0.0f, pos ? 0.0f : wp);
        uint2 o;
        o.x = *(unsigned int*)&ab;
        o.y = *(unsigned int*)&ws;
        rabw[e] = o;
    }
    if (e < SS * UU) {
        float sg = sensory_sigma[e], m = sensory_mu[e];
        float wp = log1pf(expf(sensory_w[e]));
        bool pos = sensory_erev[e] > 0.0f;
        __half2 ab = __floats2half2_rn(-sg * LOG2E, sg * m * LOG2E);
        __half2 ws = __floats2half2_rn(pos ? wp : 0.0f, pos ? 0.0f : wp);
        uint2 o;
        o.x = *(unsigned int*)&ab;
        o.y = *(unsigned int*)&ws;
        sabw[e] = o;
    }
    if (e < UU) {
        float gl = log1pf(expf(gleak[e]));
        float c = log1pf(expf(cm[e])) * 6.0f;   // ODE_UNFOLDS=6, ts=1
        cmt[e] = c;
        gnum[e] = gl * vleak[e];
        cden[e] = c + gl + 1e-8f;
    }
}

// one sigmoid-weighted accumulation step (f16 path)
#define STEP(ABBITS, WBITS, VK) do {                                        \
    union { unsigned int ui; __half2 h; } cab_, cw_;                        \
    cab_.ui = (ABBITS); cw_.ui = (WBITS);                                   \
    __half z_ = __hfma(__low2half(cab_.h), (VK), __high2half(cab_.h));      \
    __half ex_ = hexp2(z_);                                                 \
    __half s_ = hrcp(__hadd(ex_, __float2half(1.0f)));                      \
    acc2 = __hfma2(cw_.h, __half2half2(s_), acc2);                          \
} while (0)

#define FLUSH() do {                                                        \
    float2 fl_ = __half22float2(acc2);                                      \
    P += fl_.x; N += fl_.y;                                                 \
    acc2 = __half2half2(__float2half(0.0f));                                \
} while (0)

// ---------------- main kernel: 1 block = 1 batch element, 16 waves ----------------
// wave (qi=wv&3, qj=wv>>2): column j = 64*qj + l.
// i-rows per wave: 48 in registers (rows 48qi..48qi+48) + 16 from LDS (rows 192+16qi..+16).
// v is lane-distributed: lane l holds v[u(l)], u = l<48 ? 48qi+l : 192+16qi+(l-48);
// readlane broadcasts exactly the rows this wave needs. 1 barrier per unfold.
//
// Convergence skip: the ODE map contracts ~0.07x/unfold (cm_t ~ 2.9 vs den ~ 30-40),
// so v hits its fixed point to <1e-5 within ~5 unfolds. Once a whole unfold changes
// no unit by > CONV_EPS, all later unfolds this timestep (incl. all ACT steps n>=1)
// are identity: skip them and reuse the cached halting prob. Verdict is carried in a
// triple-buffered LDS flag so it is race-free with ONE barrier per unfold (lag 2).
__global__ __launch_bounds__(1024, 4) void ltc_kernel(
    const float* __restrict__ x,
    const float* __restrict__ input_w, const float* __restrict__ input_b,
    const float* __restrict__ halt_w, const float* __restrict__ halt_b,
    const float* __restrict__ out_w, const float* __restrict__ out_b,
    const uint2* __restrict__ rabw, const uint2* __restrict__ sabw,
    const float* __restrict__ cmt_g, const float* __restrict__ gnum_g,
    const float* __restrict__ cden_g,
    float* __restrict__ readout, float* __restrict__ h_state, float* __restrict__ ponder_out)
{
    const int b = blockIdx.x, tid = threadIdx.x;
    const int wv = tid >> 6, l = tid & 63;
    const int qi = wv & 3, qj = wv >> 2;
    const int j = (qj << 6) + l;
    const int u = (l < 48) ? (48 * qi + l) : (192 + 16 * qi + (l - 48));

    __shared__ uint2 rlds[64 * UU];          // 128 KB: rows 192..255
    __shared__ float2 part[2][4][UU];        // 16 KB: (P,N) partials, double-buffered
    __shared__ __half xinh[SS];
    __shared__ float red[4];
    __shared__ int viol[3];                  // triple-buffered "this unfold changed v" flag

    // stage LDS-resident rows (once)
    for (int m = 0; m < 16; ++m) {
        int f = m * 1024 + tid;
        rlds[f] = rabw[(192 << 8) + f];
    }

    // register-resident rows (once): 96 VGPRs
    unsigned int rp_ab[48], rp_w[48];
#pragma unroll
    for (int k = 0; k < 48; ++k) {
        uint2 tp = rabw[((48 * qi + k) << 8) + j];
        rp_ab[k] = tp.x; rp_w[k] = tp.y;
    }

    const float cmtu = cmt_g[u], gnu = gnum_g[u], cdu = cden_g[u];
    const float hwu = halt_w[u], owu = out_w[u], obu = out_b[u];
    const float hb = halt_b[0];
    float iw = 0.f, ibv = 0.f;
    if (tid < SS) { iw = input_w[tid]; ibv = input_b[tid]; }

    float v = 0.0f;
    int vhb = 0;                  // f16 bits of v (for readlane broadcast)
    float pond = 0.0f;
    __syncthreads();

    for (int t = 0; t < TT; ++t) {
        // ---- input mapping (f16 for broadcast use) ----
        if (tid < SS)
            xinh[tid] = __float2half(fmaf(x[((size_t)b * TT + t) * SS + tid], iw, ibv));
        __syncthreads();

        // ---- sensory partials: rows [32qi, 32qi+32), streamed from L2, chunk=4 ----
        // (also reset viol[0] behind the barrier above; first conflicting access is
        //  unfold 0's flag-write, which is >=2 barriers later)
        if (tid == 0) viol[0] = 0;
        {
            float P = 0.f, N = 0.f;
            __half2 acc2 = __half2half2(__float2half(0.0f));
#pragma unroll 1
            for (int c = 0; c < 8; ++c) {
                uint2 buf[4];
#pragma unroll
                for (int m = 0; m < 4; ++m)
                    buf[m] = sabw[((32 * qi + 4 * c + m) << 8) + j];
#pragma unroll
                for (int m = 0; m < 4; ++m) {
                    __half xh = xinh[32 * qi + 4 * c + m];
                    STEP(buf[m].x, buf[m].y, xh);
                }
                FLUSH();
            }
            part[0][qi][j] = make_float2(P, N);
        }
        __syncthreads();
        float basen, based;
        {
            float2 s0 = part[0][0][u], s1 = part[0][1][u];
            float2 s2 = part[0][2][u], s3 = part[0][3][u];
            float Ps = s0.x + s1.x + s2.x + s3.x;
            float Ns = s0.y + s1.y + s2.y + s3.y;
            basen = (Ps - Ns) + gnu;
            based = (Ps + Ns) + cdu;
        }

        int pb = 1;
        float accA = 0.0f, halt_sum = 0.0f, rem = 0.0f;
        int nupd = 0;
        int g3 = 0;              // unfold index mod 3 (across ACT steps within this t)
        int g = 0;               // unfold index within this t
        bool tconv = false;      // fixed point reached -> all further unfolds identity
        float pr = 0.0f;         // cached halting prob (valid while tconv)

        // ---- ACT loop (uniform early exit) ----
#pragma unroll 1
        for (int n = 0; n < 10; ++n) {
            bool ran = !tconv;
            if (ran) {
#pragma unroll 1
                for (int uu = 0; uu < 6 && !tconv; ++uu) {
                    // ---- A: partials from current vhb ----
                    float P = 0.f, N = 0.f;
                    __half2 acc2 = __half2half2(__float2half(0.0f));
#pragma unroll
                    for (int k = 0; k < 48; ++k) {
                        __half vk = __ushort_as_half(
                            (unsigned short)__builtin_amdgcn_readlane(vhb, k));
                        STEP(rp_ab[k], rp_w[k], vk);
                        if ((k & 15) == 15) FLUSH();
                    }
#pragma unroll
                    for (int k = 0; k < 16; ++k) {
                        uint2 prr = rlds[((16 * qi + k) << 8) + j];
                        __half vk = __ushort_as_half(
                            (unsigned short)__builtin_amdgcn_readlane(vhb, 48 + k));
                        STEP(prr.x, prr.y, vk);
                    }
                    FLUSH();
                    part[pb][qi][j] = make_float2(P, N);
                    __syncthreads();
                    // ---- B: redundant per-wave v-update for own units ----
                    float2 p0 = part[pb][0][u], p1 = part[pb][1][u];
                    float2 p2 = part[pb][2][u], p3 = part[pb][3][u];
                    float Pt = p0.x + p1.x + p2.x + p3.x;
                    float Nt = p0.y + p1.y + p2.y + p3.y;
                    float num = (Pt - Nt) + basen;
                    float den = (Pt + Nt) + based;
                    float vn = fmaf(cmtu, v, num) * __builtin_amdgcn_rcpf(den);
                    float dv = fabsf(vn - v);
                    v = vn;
                    vhb = (int)__half_as_ushort(__float2half(v));
                    // convergence bookkeeping (indices g3 [write], g3-1 [read],
                    // g3+1 [reset] are distinct mod 3; reads/writes of the same slot
                    // are always separated by the per-unfold barrier)
                    int aw = __all(dv <= CONV_EPS);
                    if (l == 0 && !aw) viol[g3] = 1;
                    int gz = g3 + 1; if (gz == 3) gz = 0;
                    if (tid == 0) viol[gz] = 0;
                    if (g >= 1) {
                        int gr = g3 - 1; if (gr < 0) gr = 2;
                        if (viol[gr] == 0) tconv = true;   // unfold g-1 was identity
                    }
                    pb ^= 1; ++g; g3 = gz;
                }

                // halting p = sigmoid(v . halt_w + hb); qj==0 waves hold all 256 units
                if (qj == 0) {
                    float hp = v * hwu;
                    hp += __shfl_down(hp, 32, 64);
                    hp += __shfl_down(hp, 16, 64);
                    hp += __shfl_down(hp, 8, 64);
                    hp += __shfl_down(hp, 4, 64);
                    hp += __shfl_down(hp, 2, 64);
                    hp += __shfl_down(hp, 1, 64);
                    if (l == 0) red[qi] = hp;
                }
                __syncthreads();
                float dot = red[0] + red[1] + red[2] + red[3] + hb;
                pr = __builtin_amdgcn_rcpf(1.0f + __builtin_amdgcn_exp2f(-dot * LOG2E));
            }
            // scalar ACT accounting (exact reference semantics; runs even when skipped)
            float new_sum = halt_sum + pr;
            bool halting = (n == 9) || (new_sum >= 0.99f);
            float r = 1.0f - halt_sum;
            float wgt = halting ? r : pr;
            accA = fmaf(wgt, v, accA);
            if (halting) rem += r;
            halt_sum = new_sum;
            ++nupd;
            if (halting) break;
        }

        // ---- t epilogue: new_state = accA ----
        if (qj == 0)
            readout[((size_t)b * TT + t) * UU + u] = fmaf(accA, owu, obu);
        v = accA;
        vhb = (int)__half_as_ushort(__float2half(v));
        pond += (float)nupd + rem;
    }

    if (qj == 0) h_state[(size_t)b * UU + u] = v;
    if (tid == 0) atomicAdd(ponder_out, pond * (1.0f / BB));
}

// ---------------- launch ----------------
extern "C" void kernel_launch(void* const* d_in, const int* in_sizes, int n_in,
                              void* d_out, int out_size, void* d_ws, size_t ws_size,
                              hipStream_t stream)
{
    const float* x             = (const float*)d_in[0];
    const float* input_w       = (const float*)d_in[1];
    const float* input_b       = (const float*)d_in[2];
    const float* sensory_w     = (const float*)d_in[3];
    const float* sensory_mu    = (const float*)d_in[4];
    const float* sensory_sigma = (const float*)d_in[5];
    const float* sensory_erev  = (const float*)d_in[6];
    const float* w             = (const float*)d_in[7];
    const float* mu            = (const float*)d_in[8];
    const float* sigma         = (const float*)d_in[9];
    const float* erev          = (const float*)d_in[10];
    const float* gleak         = (const float*)d_in[11];
    const float* vleak         = (const float*)d_in[12];
    const float* cm            = (const float*)d_in[13];
    const float* output_w      = (const float*)d_in[14];
    const float* output_b      = (const float*)d_in[15];
    const float* halt_w        = (const float*)d_in[16];
    const float* halt_b        = (const float*)d_in[17];

    float* readout = (float*)d_out;
    float* h_state = readout + (size_t)BB * TT * UU;
    float* ponder  = h_state + (size_t)BB * UU;

    char* wsb = (char*)d_ws;
    uint2* rabw = (uint2*)wsb;  wsb += (size_t)UU * UU * sizeof(uint2);
    uint2* sabw = (uint2*)wsb;  wsb += (size_t)SS * UU * sizeof(uint2);
    float* cmt  = (float*)wsb;  wsb += (size_t)UU * 4;
    float* gnum = (float*)wsb;  wsb += (size_t)UU * 4;
    float* cden = (float*)wsb;  wsb += (size_t)UU * 4;

    hipMemsetAsync(ponder, 0, sizeof(float), stream);
    prep_kernel<<<(UU * UU) / 256, 256, 0, stream>>>(
        sensory_w, sensory_mu, sensory_sigma, sensory_erev,
        w, mu, sigma, erev, gleak, vleak, cm,
        rabw, sabw, cmt, gnum, cden);
    ltc_kernel<<<BB, 1024, 0, stream>>>(
        x, input_w, input_b, halt_w, halt_b, output_w, output_b,
        rabw, sabw, cmt, gnum, cden,
        readout, h_state, ponder);
}

// Round 2
// 5036.395 us; speedup vs baseline: 2.3314x; 1.4327x over previous
//
#include <hip/hip_runtime.h>
#include <hip/hip_fp16.h>

#define LOG2E 1.44269504088896340736f
#define BB 256
#define TT 128
#define SS 128
#define UU 256
// |dv| threshold for "unfold was identity". Must sit ABOVE one f16 ulp at |v|~[0.5,1)
// (4.88e-4): v is broadcast as f16, so the converged discrete map either fixes on one
// f16 code (dv=0) or dithers between adjacent codes at exactly 1 ulp. 4e-5 (R1) missed
// the dither case -> ~20% of (b,t) tiles never skipped. Residual drift after freeze is
// <= eps * 0.07/(1-0.07) ~ 4.5e-5 (contraction ~0.07/unfold), below f16 noise.
#define CONV_EPS 6.0e-4f

// ---------------- parameter precompute ----------------
// sigmoid(sigma*(v-mu)) = 1/(1+2^(a*v+b)), a=-sigma*log2e, b=sigma*mu*log2e
// wsel = (softplus(w),0) if erev>0 else (0,softplus(w))  ->  num=P-N, den=P+N
// packed per pair: uint2{ half2(a,b), half2(wP,wN) }  (8 bytes)
__global__ __launch_bounds__(256) void prep_kernel(
    const float* __restrict__ sensory_w, const float* __restrict__ sensory_mu,
    const float* __restrict__ sensory_sigma, const float* __restrict__ sensory_erev,
    const float* __restrict__ w, const float* __restrict__ mu,
    const float* __restrict__ sigma, const float* __restrict__ erev,
    const float* __restrict__ gleak, const float* __restrict__ vleak,
    const float* __restrict__ cm,
    uint2* __restrict__ rabw, uint2* __restrict__ sabw,
    float* __restrict__ cmt, float* __restrict__ gnum, float* __restrict__ cden)
{
    int e = blockIdx.x * 256 + threadIdx.x;
    if (e < UU * UU) {
        float sg = sigma[e], m = mu[e];
        float wp = log1pf(expf(w[e]));
        bool pos = erev[e] > 0.0f;
        __half2 ab = __floats2half2_rn(-sg * LOG2E, sg * m * LOG2E);
        __half2 ws = __floats2half2_rn(pos ? wp : 0.0f, pos ? 0.0f : wp);
        uint2 o;
        o.x = *(unsigned int*)&ab;
        o.y = *(unsigned int*)&ws;
        rabw[e] = o;
    }
    if (e < SS * UU) {
        float sg = sensory_sigma[e], m = sensory_mu[e];
        float wp = log1pf(expf(sensory_w[e]));
        bool pos = sensory_erev[e] > 0.0f;
        __half2 ab = __floats2half2_rn(-sg * LOG2E, sg * m * LOG2E);
        __half2 ws = __floats2half2_rn(pos ? wp : 0.0f, pos ? 0.0f : wp);
        uint2 o;
        o.x = *(unsigned int*)&ab;
        o.y = *(unsigned int*)&ws;
        sabw[e] = o;
    }
    if (e < UU) {
        float gl = log1pf(expf(gleak[e]));
        float c = log1pf(expf(cm[e])) * 6.0f;   // ODE_UNFOLDS=6, ts=1
        cmt[e] = c;
        gnum[e] = gl * vleak[e];
        cden[e] = c + gl + 1e-8f;
    }
}

// one sigmoid-weighted accumulation step (f16 path)
#define STEP(ABBITS, WBITS, VK) do {                                        \
    union { unsigned int ui; __half2 h; } cab_, cw_;                        \
    cab_.ui = (ABBITS); cw_.ui = (WBITS);                                   \
    __half z_ = __hfma(__low2half(cab_.h), (VK), __high2half(cab_.h));      \
    __half ex_ = hexp2(z_);                                                 \
    __half s_ = hrcp(__hadd(ex_, __float2half(1.0f)));                      \
    acc2 = __hfma2(cw_.h, __half2half2(s_), acc2);                          \
} while (0)

#define FLUSH() do {                                                        \
    float2 fl_ = __half22float2(acc2);                                      \
    P += fl_.x; N += fl_.y;                                                 \
    acc2 = __half2half2(__float2half(0.0f));                                \
} while (0)

// ---------------- main kernel: 1 block = 1 batch element, 16 waves ----------------
// wave (qi=wv&3, qj=wv>>2): column j = 64*qj + l.
// i-rows per wave: 48 in registers (rows 48qi..48qi+48) + 16 from LDS (rows 192+16qi..+16).
// v is lane-distributed: lane l holds v[u(l)], u = l<48 ? 48qi+l : 192+16qi+(l-48);
// readlane broadcasts exactly the rows this wave needs. 1 barrier per unfold.
//
// Convergence skip: the ODE map contracts ~0.07x/unfold (cm_t ~ 2.9 vs den ~ 30-40),
// so v hits its (f16-quantized) fixed point within a few unfolds. Once a whole unfold
// changes no unit by > CONV_EPS, all later unfolds this timestep (incl. all ACT steps
// n>=1) are identity: skip them and reuse the cached halting prob. Verdict is carried
// in a triple-buffered LDS flag so it is race-free with ONE barrier per unfold.
__global__ __launch_bounds__(1024, 4) void ltc_kernel(
    const float* __restrict__ x,
    const float* __restrict__ input_w, const float* __restrict__ input_b,
    const float* __restrict__ halt_w, const float* __restrict__ halt_b,
    const float* __restrict__ out_w, const float* __restrict__ out_b,
    const uint2* __restrict__ rabw, const uint2* __restrict__ sabw,
    const float* __restrict__ cmt_g, const float* __restrict__ gnum_g,
    const float* __restrict__ cden_g,
    float* __restrict__ readout, float* __restrict__ h_state, float* __restrict__ ponder_out)
{
    const int b = blockIdx.x, tid = threadIdx.x;
    const int wv = tid >> 6, l = tid & 63;
    const int qi = wv & 3, qj = wv >> 2;
    const int j = (qj << 6) + l;
    const int u = (l < 48) ? (48 * qi + l) : (192 + 16 * qi + (l - 48));

    __shared__ uint2 rlds[64 * UU];          // 128 KB: rows 192..255
    __shared__ float2 part[2][4][UU];        // 16 KB: (P,N) partials, double-buffered
    __shared__ __half xinh[SS];
    __shared__ float red[4];
    __shared__ int viol[3];                  // triple-buffered "this unfold changed v" flag

    // stage LDS-resident rows (once)
    for (int m = 0; m < 16; ++m) {
        int f = m * 1024 + tid;
        rlds[f] = rabw[(192 << 8) + f];
    }

    // register-resident rows (once): 96 VGPRs
    unsigned int rp_ab[48], rp_w[48];
#pragma unroll
    for (int k = 0; k < 48; ++k) {
        uint2 tp = rabw[((48 * qi + k) << 8) + j];
        rp_ab[k] = tp.x; rp_w[k] = tp.y;
    }

    const float cmtu = cmt_g[u], gnu = gnum_g[u], cdu = cden_g[u];
    const float hwu = halt_w[u], owu = out_w[u], obu = out_b[u];
    const float hb = halt_b[0];
    float iw = 0.f, ibv = 0.f;
    if (tid < SS) { iw = input_w[tid]; ibv = input_b[tid]; }

    float v = 0.0f;
    int vhb = 0;                  // f16 bits of v (for readlane broadcast)
    float pond = 0.0f;
    __syncthreads();

    for (int t = 0; t < TT; ++t) {
        // ---- input mapping (f16 for broadcast use) ----
        if (tid < SS)
            xinh[tid] = __float2half(fmaf(x[((size_t)b * TT + t) * SS + tid], iw, ibv));
        __syncthreads();

        // ---- sensory partials: rows [32qi, 32qi+32), streamed from L2, chunk=4 ----
        // (also reset viol[0] behind the barrier above; first conflicting access is
        //  unfold 0's flag-write, which is >=2 barriers later)
        if (tid == 0) viol[0] = 0;
        {
            float P = 0.f, N = 0.f;
            __half2 acc2 = __half2half2(__float2half(0.0f));
#pragma unroll 1
            for (int c = 0; c < 8; ++c) {
                uint2 buf[4];
#pragma unroll
                for (int m = 0; m < 4; ++m)
                    buf[m] = sabw[((32 * qi + 4 * c + m) << 8) + j];
#pragma unroll
                for (int m = 0; m < 4; ++m) {
                    __half xh = xinh[32 * qi + 4 * c + m];
                    STEP(buf[m].x, buf[m].y, xh);
                }
                FLUSH();
            }
            part[0][qi][j] = make_float2(P, N);
        }
        __syncthreads();
        float basen, based;
        {
            float2 s0 = part[0][0][u], s1 = part[0][1][u];
            float2 s2 = part[0][2][u], s3 = part[0][3][u];
            float Ps = s0.x + s1.x + s2.x + s3.x;
            float Ns = s0.y + s1.y + s2.y + s3.y;
            basen = (Ps - Ns) + gnu;
            based = (Ps + Ns) + cdu;
        }

        int pb = 1;
        float accA = 0.0f, halt_sum = 0.0f, rem = 0.0f;
        int nupd = 0;
        int g3 = 0;              // unfold index mod 3 (across ACT steps within this t)
        int g = 0;               // unfold index within this t
        bool tconv = false;      // fixed point reached -> all further unfolds identity
        float pr = 0.0f;         // cached halting prob (valid while tconv)

        // ---- ACT loop (uniform early exit) ----
#pragma unroll 1
        for (int n = 0; n < 10; ++n) {
            bool ran = !tconv;
            if (ran) {
#pragma unroll 1
                for (int uu = 0; uu < 6 && !tconv; ++uu) {
                    // ---- A: partials from current vhb ----
                    float P = 0.f, N = 0.f;
                    __half2 acc2 = __half2half2(__float2half(0.0f));
#pragma unroll
                    for (int k = 0; k < 48; ++k) {
                        __half vk = __ushort_as_half(
                            (unsigned short)__builtin_amdgcn_readlane(vhb, k));
                        STEP(rp_ab[k], rp_w[k], vk);
                        if ((k & 15) == 15) FLUSH();
                    }
#pragma unroll
                    for (int k = 0; k < 16; ++k) {
                        uint2 prr = rlds[((16 * qi + k) << 8) + j];
                        __half vk = __ushort_as_half(
                            (unsigned short)__builtin_amdgcn_readlane(vhb, 48 + k));
                        STEP(prr.x, prr.y, vk);
                    }
                    FLUSH();
                    part[pb][qi][j] = make_float2(P, N);
                    __syncthreads();
                    // ---- B: redundant per-wave v-update for own units ----
                    float2 p0 = part[pb][0][u], p1 = part[pb][1][u];
                    float2 p2 = part[pb][2][u], p3 = part[pb][3][u];
                    float Pt = p0.x + p1.x + p2.x + p3.x;
                    float Nt = p0.y + p1.y + p2.y + p3.y;
                    float num = (Pt - Nt) + basen;
                    float den = (Pt + Nt) + based;
                    float vn = fmaf(cmtu, v, num) * __builtin_amdgcn_rcpf(den);
                    float dv = fabsf(vn - v);
                    v = vn;
                    vhb = (int)__half_as_ushort(__float2half(v));
                    // convergence bookkeeping (indices g3 [write], g3-1 [read],
                    // g3+1 [reset] are distinct mod 3; reads/writes of the same slot
                    // are always separated by the per-unfold barrier)
                    int aw = __all(dv <= CONV_EPS);
                    if (l == 0 && !aw) viol[g3] = 1;
                    int gz = g3 + 1; if (gz == 3) gz = 0;
                    if (tid == 0) viol[gz] = 0;
                    if (g >= 1) {
                        int gr = g3 - 1; if (gr < 0) gr = 2;
                        if (viol[gr] == 0) tconv = true;   // unfold g-1 was identity
                    }
                    pb ^= 1; ++g; g3 = gz;
                }

                // halting p = sigmoid(v . halt_w + hb); qj==0 waves hold all 256 units
                if (qj == 0) {
                    float hp = v * hwu;
                    hp += __shfl_down(hp, 32, 64);
                    hp += __shfl_down(hp, 16, 64);
                    hp += __shfl_down(hp, 8, 64);
                    hp += __shfl_down(hp, 4, 64);
                    hp += __shfl_down(hp, 2, 64);
                    hp += __shfl_down(hp, 1, 64);
                    if (l == 0) red[qi] = hp;
                }
                __syncthreads();
                float dot = red[0] + red[1] + red[2] + red[3] + hb;
                pr = __builtin_amdgcn_rcpf(1.0f + __builtin_amdgcn_exp2f(-dot * LOG2E));
            }
            // scalar ACT accounting (exact reference semantics; runs even when skipped)
            float new_sum = halt_sum + pr;
            bool halting = (n == 9) || (new_sum >= 0.99f);
            float r = 1.0f - halt_sum;
            float wgt = halting ? r : pr;
            accA = fmaf(wgt, v, accA);
            if (halting) rem += r;
            halt_sum = new_sum;
            ++nupd;
            if (halting) break;
        }

        // ---- t epilogue: new_state = accA ----
        if (qj == 0)
            readout[((size_t)b * TT + t) * UU + u] = fmaf(accA, owu, obu);
        v = accA;
        vhb = (int)__half_as_ushort(__float2half(v));
        pond += (float)nupd + rem;
    }

    if (qj == 0) h_state[(size_t)b * UU + u] = v;
    if (tid == 0) atomicAdd(ponder_out, pond * (1.0f / BB));
}

// ---------------- launch ----------------
extern "C" void kernel_launch(void* const* d_in, const int* in_sizes, int n_in,
                              void* d_out, int out_size, void* d_ws, size_t ws_size,
                              hipStream_t stream)
{
    const float* x             = (const float*)d_in[0];
    const float* input_w       = (const float*)d_in[1];
    const float* input_b       = (const float*)d_in[2];
    const float* sensory_w     = (const float*)d_in[3];
    const float* sensory_mu    = (const float*)d_in[4];
    const float* sensory_sigma = (const float*)d_in[5];
    const float* sensory_erev  = (const float*)d_in[6];
    const float* w             = (const float*)d_in[7];
    const float* mu            = (const float*)d_in[8];
    const float* sigma         = (const float*)d_in[9];
    const float* erev          = (const float*)d_in[10];
    const float* gleak         = (const float*)d_in[11];
    const float* vleak         = (const float*)d_in[12];
    const float* cm            = (const float*)d_in[13];
    const float* output_w      = (const float*)d_in[14];
    const float* output_b      = (const float*)d_in[15];
    const float* halt_w        = (const float*)d_in[16];
    const float* halt_b       = (const float*)d_in[17];

    float* readout = (float*)d_out;
    float* h_state = readout + (size_t)BB * TT * UU;
    float* ponder  = h_state + (size_t)BB * UU;

    char* wsb = (char*)d_ws;
    uint2* rabw = (uint2*)wsb;  wsb += (size_t)UU * UU * sizeof(uint2);
    uint2* sabw = (uint2*)wsb;  wsb += (size_t)SS * UU * sizeof(uint2);
    float* cmt  = (float*)wsb;  wsb += (size_t)UU * 4;
    float* gnum = (float*)wsb;  wsb += (size_t)UU * 4;
    float* cden = (float*)wsb;  wsb += (size_t)UU * 4;

    hipMemsetAsync(ponder, 0, sizeof(float), stream);
    prep_kernel<<<(UU * UU) / 256, 256, 0, stream>>>(
        sensory_w, sensory_mu, sensory_sigma, sensory_erev,
        w, mu, sigma, erev, gleak, vleak, cm,
        rabw, sabw, cmt, gnum, cden);
    ltc_kernel<<<BB, 1024, 0, stream>>>(
        x, input_w, input_b, halt_w, halt_b, output_w, output_b,
        rabw, sabw, cmt, gnum, cden,
        readout, h_state, ponder);
}